// Round 4
// baseline (631.040 us; speedup 1.0000x reference)
//
#include <hip/hip_runtime.h>
#include <math.h>

#define FIN 78
#define HD1 512
#define D2  128
#define CR1 32      // layer-1 LDS row-cache capacity (rows of 512 floats)
#define LCAP1 512   // layer-1 LDS logit capacity (edges)
#define CR2 64      // layer-2 LDS row-cache capacity (rows of 128 floats)
#define LCAP2 1024  // layer-2 LDS logit capacity

__device__ __forceinline__ float lrelu(float x) { return x > 0.f ? x : 0.2f * x; }
__device__ __forceinline__ float elu(float x)   { return x > 0.f ? x : expf(x) - 1.f; }

// ---------- layer-1 input GEMM: x[N,78] @ {Wl1,Wr1}[78,512] + bias ----------
__global__ void gemm1_k(const float* __restrict__ x,
                        const float* __restrict__ Wl, const float* __restrict__ bl,
                        const float* __restrict__ Wr, const float* __restrict__ br,
                        float* __restrict__ xl, float* __restrict__ xr, int N)
{
    __shared__ float xs[4][FIN];
    int row0 = blockIdx.x * 4;
    int t = threadIdx.x;
    for (int idx = t; idx < 4 * FIN; idx += 256) {
        int r = idx / FIN, k = idx - r * FIN;
        int row = row0 + r;
        xs[r][k] = (row < N) ? x[(size_t)row * FIN + k] : 0.f;
    }
    __syncthreads();
    for (int i = 0; i < 4; ++i) {
        int j = t + i * 256;                 // 0..1023
        const float* W; float* out; int col; float b;
        if (j < HD1) { W = Wl; out = xl; col = j;       b = bl[col]; }
        else         { W = Wr; out = xr; col = j - HD1; b = br[col]; }
        float a0 = b, a1 = b, a2 = b, a3 = b;
        for (int k = 0; k < FIN; ++k) {
            float w = W[k * HD1 + col];
            a0 += xs[0][k] * w; a1 += xs[1][k] * w;
            a2 += xs[2][k] * w; a3 += xs[3][k] * w;
        }
        if (row0 + 0 < N) out[(size_t)(row0 + 0) * HD1 + col] = a0;
        if (row0 + 1 < N) out[(size_t)(row0 + 1) * HD1 + col] = a1;
        if (row0 + 2 < N) out[(size_t)(row0 + 2) * HD1 + col] = a2;
        if (row0 + 3 < N) out[(size_t)(row0 + 3) * HD1 + col] = a3;
    }
}

// ---------- layer-2 input GEMM: h1[N,512] @ {Wl2,Wr2}[512,128] + bias ----------
__global__ void gemm2_k(const float* __restrict__ h,
                        const float* __restrict__ Wl, const float* __restrict__ bl,
                        const float* __restrict__ Wr, const float* __restrict__ br,
                        float* __restrict__ xl, float* __restrict__ xr, int N)
{
    __shared__ float hs[8][HD1];
    int row0 = blockIdx.x * 8;
    int t = threadIdx.x;
    for (int idx = t; idx < 8 * HD1; idx += 256) {
        int r = idx >> 9, k = idx & 511;
        int row = row0 + r;
        hs[r][k] = (row < N) ? h[(size_t)row * HD1 + k] : 0.f;
    }
    __syncthreads();
    const float* W; float* out; int col; float b;
    if (t < D2) { W = Wl; out = xl; col = t;      b = bl[col]; }
    else        { W = Wr; out = xr; col = t - D2; b = br[col]; }
    float acc[8];
#pragma unroll
    for (int r = 0; r < 8; ++r) acc[r] = b;
    for (int k = 0; k < HD1; ++k) {
        float w = W[k * D2 + col];
#pragma unroll
        for (int r = 0; r < 8; ++r) acc[r] += hs[r][k] * w;
    }
    for (int r = 0; r < 8; ++r) {
        int row = row0 + r;
        if (row < N) out[(size_t)row * D2 + col] = acc[r];
    }
}

// ---------- CSR build over destination nodes ----------
__global__ void count_k(const int* __restrict__ ei, int E, int Etot, int* __restrict__ counts)
{
    int e = blockIdx.x * 256 + threadIdx.x;
    if (e >= Etot) return;
    int dst = (e < E) ? ei[E + e] : (e - E);
    atomicAdd(&counts[dst], 1);
}

__global__ void scan_k(const int* __restrict__ counts, int* __restrict__ row_ptr,
                       int* __restrict__ offs, int N)
{
    __shared__ int sdata[1024];
    int t = threadIdx.x;
    int chunk = (N + 1023) / 1024;
    int lo = t * chunk, hi = min(lo + chunk, N);
    int p = 0;
    for (int i = lo; i < hi; ++i) p += counts[i];
    sdata[t] = p;
    __syncthreads();
    for (int off = 1; off < 1024; off <<= 1) {
        int v = (t >= off) ? sdata[t - off] : 0;
        __syncthreads();
        sdata[t] += v;
        __syncthreads();
    }
    int run = sdata[t] - p;   // exclusive prefix
    for (int i = lo; i < hi; ++i) { row_ptr[i] = run; offs[i] = run; run += counts[i]; }
    if (t == 1023) row_ptr[N] = sdata[1023];
}

__global__ void scatter_k(const int* __restrict__ ei, int E, int Etot,
                          int* __restrict__ offs, int* __restrict__ csr_src,
                          int* __restrict__ csr_eid)
{
    int e = blockIdx.x * 256 + threadIdx.x;
    if (e >= Etot) return;
    int src, dst;
    if (e < E) { src = ei[e]; dst = ei[E + e]; } else { src = dst = e - E; }
    int pos = atomicAdd(&offs[dst], 1);
    csr_src[pos] = src;
    csr_eid[pos] = e;
}

// ---------- layer-1 fused: scores + softmax + aggregate + bias + ELU ----------
// one block (256 thr = 4 waves) per destination node
__global__ __launch_bounds__(256, 2)
void fused1_k(const int* __restrict__ row_ptr, const int* __restrict__ csr_src,
              const float* __restrict__ xl, const float* __restrict__ xr,
              const float* __restrict__ att, const float* __restrict__ bias,
              float* __restrict__ spill, float* __restrict__ out)
{
    __shared__ float xr_s[HD1];
    __shared__ float cache[CR1][HD1];
    __shared__ float lg[LCAP1 * 4];
    __shared__ float smax[4], sinv[4];

    int v = blockIdx.x;
    int t = threadIdx.x;
    int w = t >> 6, lane = t & 63;
    int base = row_ptr[v], deg = row_ptr[v + 1] - base;

    for (int c = t; c < HD1; c += 256) xr_s[c] = xr[(size_t)v * HD1 + c];
    __syncthreads();

    // ---- pass 1: per-edge logits (wave = edge), cache rows ----
    int c0 = lane * 8;                   // head = lane>>4
    float4 t0 = *(const float4*)(att + c0);
    float4 t1 = *(const float4*)(att + c0 + 4);
    float4 b0 = *(const float4*)&xr_s[c0];
    float4 b1 = *(const float4*)&xr_s[c0 + 4];
    for (int i = w; i < deg; i += 4) {
        int src = csr_src[base + i];
        const float4* pa = (const float4*)(xl + (size_t)src * HD1 + c0);
        float4 a0 = pa[0], a1 = pa[1];
        if (i < CR1) {
            *(float4*)&cache[i][c0]     = a0;
            *(float4*)&cache[i][c0 + 4] = a1;
        }
        float s = t0.x * lrelu(a0.x + b0.x) + t0.y * lrelu(a0.y + b0.y)
                + t0.z * lrelu(a0.z + b0.z) + t0.w * lrelu(a0.w + b0.w)
                + t1.x * lrelu(a1.x + b1.x) + t1.y * lrelu(a1.y + b1.y)
                + t1.z * lrelu(a1.z + b1.z) + t1.w * lrelu(a1.w + b1.w);
        for (int off = 1; off < 16; off <<= 1) s += __shfl_xor(s, off);
        if ((lane & 15) == 0) {
            int h = lane >> 4;
            if (i < LCAP1) lg[i * 4 + h] = s;
            else           spill[(size_t)(base + i) * 4 + h] = s;
        }
    }
    __syncthreads();

    // ---- softmax: wave w owns head w ----
    {
        float m = -INFINITY;
        for (int i = lane; i < deg; i += 64) {
            float lv = (i < LCAP1) ? lg[i * 4 + w] : spill[(size_t)(base + i) * 4 + w];
            m = fmaxf(m, lv);
        }
        for (int off = 1; off < 64; off <<= 1) m = fmaxf(m, __shfl_xor(m, off));
        float s = 0.f;
        for (int i = lane; i < deg; i += 64) {
            float lv = (i < LCAP1) ? lg[i * 4 + w] : spill[(size_t)(base + i) * 4 + w];
            s += expf(lv - m);
        }
        for (int off = 1; off < 64; off <<= 1) s += __shfl_xor(s, off);
        float rs = 1.f / s;
        if (lane == 0) { smax[w] = m; sinv[w] = rs; }
        // normalize in-LDS logits to alphas
        for (int i = lane; i < deg && i < LCAP1; i += 64)
            lg[i * 4 + w] = expf(lg[i * 4 + w] - m) * rs;
    }
    __syncthreads();

    // ---- pass 2: weighted aggregate (channels t and t+256) ----
    int h0 = t >> 7;                     // head of channel t; channel t+256 -> h0+2
    float acc0 = 0.f, acc1 = 0.f;
    for (int i = 0; i < deg; ++i) {
        float a_lo, a_hi;
        if (i < LCAP1) { a_lo = lg[i * 4 + h0]; a_hi = lg[i * 4 + h0 + 2]; }
        else {
            a_lo = expf(spill[(size_t)(base + i) * 4 + h0]     - smax[h0])     * sinv[h0];
            a_hi = expf(spill[(size_t)(base + i) * 4 + h0 + 2] - smax[h0 + 2]) * sinv[h0 + 2];
        }
        float r0, r1;
        if (i < CR1) { r0 = cache[i][t]; r1 = cache[i][t + 256]; }
        else {
            const float* row = xl + (size_t)csr_src[base + i] * HD1;
            r0 = row[t]; r1 = row[t + 256];
        }
        acc0 += a_lo * r0; acc1 += a_hi * r1;
    }
    out[(size_t)v * HD1 + t]       = elu(acc0 + bias[t]);
    out[(size_t)v * HD1 + t + 256] = elu(acc1 + bias[t + 256]);
}

// ---------- layer-2 fused: scores + softmax + aggregate + bias + ELU ----------
__global__ __launch_bounds__(256, 4)
void fused2_k(const int* __restrict__ row_ptr, const int* __restrict__ csr_src,
              const float* __restrict__ xl, const float* __restrict__ xr,
              const float* __restrict__ att, const float* __restrict__ bias,
              float* __restrict__ spill, float* __restrict__ out)
{
    __shared__ float xr_s[D2];
    __shared__ float cache[CR2][D2];
    __shared__ float lg[LCAP2];
    __shared__ float part[D2];
    __shared__ float smax_s, sinv_s;

    int v = blockIdx.x;
    int t = threadIdx.x;
    int w = t >> 6, lane = t & 63;
    int base = row_ptr[v], deg = row_ptr[v + 1] - base;

    if (t < D2) xr_s[t] = xr[(size_t)v * D2 + t];
    __syncthreads();

    // ---- pass 1: logits, wave = edge, lane holds 2 channels ----
    int c0 = lane * 2;
    float2 tt = *(const float2*)(att + c0);
    float2 bb = *(const float2*)&xr_s[c0];
    for (int i = w; i < deg; i += 4) {
        int src = csr_src[base + i];
        float2 a = *(const float2*)(xl + (size_t)src * D2 + c0);
        if (i < CR2) *(float2*)&cache[i][c0] = a;
        float s = tt.x * lrelu(a.x + bb.x) + tt.y * lrelu(a.y + bb.y);
        for (int off = 1; off < 64; off <<= 1) s += __shfl_xor(s, off);
        if (lane == 0) {
            if (i < LCAP2) lg[i] = s;
            else           spill[base + i] = s;
        }
    }
    __syncthreads();

    // ---- softmax on wave 0 ----
    if (w == 0) {
        float m = -INFINITY;
        for (int i = lane; i < deg; i += 64) {
            float lv = (i < LCAP2) ? lg[i] : spill[base + i];
            m = fmaxf(m, lv);
        }
        for (int off = 1; off < 64; off <<= 1) m = fmaxf(m, __shfl_xor(m, off));
        float s = 0.f;
        for (int i = lane; i < deg; i += 64) {
            float lv = (i < LCAP2) ? lg[i] : spill[base + i];
            s += expf(lv - m);
        }
        for (int off = 1; off < 64; off <<= 1) s += __shfl_xor(s, off);
        float rs = 1.f / s;
        if (lane == 0) { smax_s = m; sinv_s = rs; }
        for (int i = lane; i < deg && i < LCAP2; i += 64)
            lg[i] = expf(lg[i] - m) * rs;
    }
    __syncthreads();

    // ---- pass 2: aggregate; group g handles edges i = g, g+2, ... ----
    int g = t >> 7, c = t & 127;
    float acc = 0.f;
    for (int i = g; i < deg; i += 2) {
        float a = (i < LCAP2) ? lg[i]
                              : expf(spill[base + i] - smax_s) * sinv_s;
        float r;
        if (i < CR2) r = cache[i][c];
        else         r = xl[(size_t)csr_src[base + i] * D2 + c];
        acc += a * r;
    }
    if (g == 1) part[c] = acc;
    __syncthreads();
    if (g == 0) out[(size_t)v * D2 + c] = elu(acc + part[c] + bias[c]);
}

// ---------- global mean pool ----------
__global__ void pool_k(const int* __restrict__ batch, const float* __restrict__ h,
                       float* __restrict__ out, float* __restrict__ cnt, int N)
{
    int idx = blockIdx.x * 256 + threadIdx.x;
    if (idx >= N * D2) return;
    int v = idx >> 7, c = idx & 127;
    int g = batch[v];
    atomicAdd(&out[(size_t)g * D2 + c], h[idx]);
    if (c == 0) atomicAdd(&cnt[g], 1.0f);
}

__global__ void pooldiv_k(float* __restrict__ out, const float* __restrict__ cnt, int total)
{
    int idx = blockIdx.x * 256 + threadIdx.x;
    if (idx >= total) return;
    out[idx] /= fmaxf(cnt[idx >> 7], 1.0f);
}

extern "C" void kernel_launch(void* const* d_in, const int* in_sizes, int n_in,
                              void* d_out, int out_size, void* d_ws, size_t ws_size,
                              hipStream_t stream)
{
    const float* x    = (const float*)d_in[0];
    const int*   ei   = (const int*)d_in[1];
    const int*   batch= (const int*)d_in[2];
    const float* Wl1  = (const float*)d_in[3];
    const float* bl1  = (const float*)d_in[4];
    const float* Wr1  = (const float*)d_in[5];
    const float* br1  = (const float*)d_in[6];
    const float* att1 = (const float*)d_in[7];
    const float* bias1= (const float*)d_in[8];
    const float* Wl2  = (const float*)d_in[9];
    const float* bl2  = (const float*)d_in[10];
    const float* Wr2  = (const float*)d_in[11];
    const float* br2  = (const float*)d_in[12];
    const float* att2 = (const float*)d_in[13];
    const float* bias2= (const float*)d_in[14];
    float* out = (float*)d_out;

    int N    = in_sizes[2];          // batch vector length = nodes
    int E    = in_sizes[1] / 2;      // directed edges (before self-loops)
    int Etot = E + N;
    int G    = out_size / D2;

    char* ws = (char*)d_ws;
    size_t off = 0;
    auto alloc = [&](size_t bytes) -> void* {
        void* p = ws + off;
        off = (off + bytes + 255) & ~(size_t)255;
        return p;
    };
    float* xl1     = (float*)alloc((size_t)N * HD1 * 4);
    float* xr1     = (float*)alloc((size_t)N * HD1 * 4);  // layer-2 buffers alias here later
    float* h1      = (float*)alloc((size_t)N * HD1 * 4);
    float* spill1  = (float*)alloc((size_t)Etot * 4 * 4);
    int*   counts  = (int*)alloc((size_t)(N + 1) * 4);
    int*   offs    = (int*)alloc((size_t)(N + 1) * 4);
    int*   row_ptr = (int*)alloc((size_t)(N + 1) * 4);
    int*   csr_src = (int*)alloc((size_t)Etot * 4);
    int*   csr_eid = (int*)alloc((size_t)Etot * 4);
    float* poolcnt = (float*)alloc((size_t)(G + 1) * 4);
    // layer-2 aliases inside xr1 (xr1 dead after fused1_k):
    float* xl2     = xr1;
    float* xr2     = xr1 + (size_t)N * D2;
    float* h2      = xr1 + (size_t)2 * N * D2;
    float* spill2  = xr1 + (size_t)3 * N * D2;

    hipMemsetAsync(counts, 0, (size_t)(N + 1) * 4, stream);
    gemm1_k<<<(N + 3) / 4, 256, 0, stream>>>(x, Wl1, bl1, Wr1, br1, xl1, xr1, N);
    count_k<<<(Etot + 255) / 256, 256, 0, stream>>>(ei, E, Etot, counts);
    scan_k<<<1, 1024, 0, stream>>>(counts, row_ptr, offs, N);
    scatter_k<<<(Etot + 255) / 256, 256, 0, stream>>>(ei, E, Etot, offs, csr_src, csr_eid);
    fused1_k<<<N, 256, 0, stream>>>(row_ptr, csr_src, xl1, xr1, att1, bias1, spill1, h1);
    gemm2_k<<<(N + 7) / 8, 256, 0, stream>>>(h1, Wl2, bl2, Wr2, br2, xl2, xr2, N);
    fused2_k<<<N, 256, 0, stream>>>(row_ptr, csr_src, xl2, xr2, att2, bias2, spill2, h2);
    hipMemsetAsync(out, 0, (size_t)out_size * 4, stream);
    hipMemsetAsync(poolcnt, 0, (size_t)G * 4, stream);
    pool_k<<<((N * D2) + 255) / 256, 256, 0, stream>>>(batch, h2, out, poolcnt, N);
    pooldiv_k<<<(out_size + 255) / 256, 256, 0, stream>>>(out, poolcnt, out_size);
}

// Round 5
// 509.790 us; speedup vs baseline: 1.2378x; 1.2378x over previous
//
#include <hip/hip_runtime.h>
#include <math.h>

#define FIN 78
#define HD1 512
#define D2  128
#define LCAP1 128   // layer-1 LDS logit capacity (edges); max deg ~68 for this graph
#define LCAP2 256   // layer-2 LDS logit capacity

__device__ __forceinline__ float lrelu(float x) { return x > 0.f ? x : 0.2f * x; }
__device__ __forceinline__ float elu(float x)   { return x > 0.f ? x : expf(x) - 1.f; }

// ---------- layer-1 input GEMM: x[N,78] @ {Wl1,Wr1}[78,512] + bias ----------
__global__ void gemm1_k(const float* __restrict__ x,
                        const float* __restrict__ Wl, const float* __restrict__ bl,
                        const float* __restrict__ Wr, const float* __restrict__ br,
                        float* __restrict__ xl, float* __restrict__ xr, int N)
{
    __shared__ float xs[4][FIN];
    int row0 = blockIdx.x * 4;
    int t = threadIdx.x;
    for (int idx = t; idx < 4 * FIN; idx += 256) {
        int r = idx / FIN, k = idx - r * FIN;
        int row = row0 + r;
        xs[r][k] = (row < N) ? x[(size_t)row * FIN + k] : 0.f;
    }
    __syncthreads();
    for (int i = 0; i < 4; ++i) {
        int j = t + i * 256;                 // 0..1023
        const float* W; float* out; int col; float b;
        if (j < HD1) { W = Wl; out = xl; col = j;       b = bl[col]; }
        else         { W = Wr; out = xr; col = j - HD1; b = br[col]; }
        float a0 = b, a1 = b, a2 = b, a3 = b;
        for (int k = 0; k < FIN; ++k) {
            float w = W[k * HD1 + col];
            a0 += xs[0][k] * w; a1 += xs[1][k] * w;
            a2 += xs[2][k] * w; a3 += xs[3][k] * w;
        }
        if (row0 + 0 < N) out[(size_t)(row0 + 0) * HD1 + col] = a0;
        if (row0 + 1 < N) out[(size_t)(row0 + 1) * HD1 + col] = a1;
        if (row0 + 2 < N) out[(size_t)(row0 + 2) * HD1 + col] = a2;
        if (row0 + 3 < N) out[(size_t)(row0 + 3) * HD1 + col] = a3;
    }
}

// ---------- layer-2 input GEMM: h1[N,512] @ {Wl2,Wr2}[512,128] + bias ----------
__global__ void gemm2_k(const float* __restrict__ h,
                        const float* __restrict__ Wl, const float* __restrict__ bl,
                        const float* __restrict__ Wr, const float* __restrict__ br,
                        float* __restrict__ xl, float* __restrict__ xr, int N)
{
    __shared__ float hs[8][HD1];
    int row0 = blockIdx.x * 8;
    int t = threadIdx.x;
    for (int idx = t; idx < 8 * HD1; idx += 256) {
        int r = idx >> 9, k = idx & 511;
        int row = row0 + r;
        hs[r][k] = (row < N) ? h[(size_t)row * HD1 + k] : 0.f;
    }
    __syncthreads();
    const float* W; float* out; int col; float b;
    if (t < D2) { W = Wl; out = xl; col = t;      b = bl[col]; }
    else        { W = Wr; out = xr; col = t - D2; b = br[col]; }
    float acc[8];
#pragma unroll
    for (int r = 0; r < 8; ++r) acc[r] = b;
    for (int k = 0; k < HD1; ++k) {
        float w = W[k * D2 + col];
#pragma unroll
        for (int r = 0; r < 8; ++r) acc[r] += hs[r][k] * w;
    }
    for (int r = 0; r < 8; ++r) {
        int row = row0 + r;
        if (row < N) out[(size_t)row * D2 + col] = acc[r];
    }
}

// ---------- CSR build over destination nodes ----------
__global__ void count_k(const int* __restrict__ ei, int E, int Etot, int* __restrict__ counts)
{
    int e = blockIdx.x * 256 + threadIdx.x;
    if (e >= Etot) return;
    int dst = (e < E) ? ei[E + e] : (e - E);
    atomicAdd(&counts[dst], 1);
}

__global__ void scan_k(const int* __restrict__ counts, int* __restrict__ row_ptr,
                       int* __restrict__ offs, int N)
{
    __shared__ int sdata[1024];
    int t = threadIdx.x;
    int chunk = (N + 1023) / 1024;
    int lo = t * chunk, hi = min(lo + chunk, N);
    int p = 0;
    for (int i = lo; i < hi; ++i) p += counts[i];
    sdata[t] = p;
    __syncthreads();
    for (int off = 1; off < 1024; off <<= 1) {
        int v = (t >= off) ? sdata[t - off] : 0;
        __syncthreads();
        sdata[t] += v;
        __syncthreads();
    }
    int run = sdata[t] - p;   // exclusive prefix
    for (int i = lo; i < hi; ++i) { row_ptr[i] = run; offs[i] = run; run += counts[i]; }
    if (t == 1023) row_ptr[N] = sdata[1023];
}

__global__ void scatter_k(const int* __restrict__ ei, int E, int Etot,
                          int* __restrict__ offs, int* __restrict__ csr_src)
{
    int e = blockIdx.x * 256 + threadIdx.x;
    if (e >= Etot) return;
    int src, dst;
    if (e < E) { src = ei[e]; dst = ei[E + e]; } else { src = dst = e - E; }
    int pos = atomicAdd(&offs[dst], 1);
    csr_src[pos] = src;
}

// ---------- layer-1 fused: scores + softmax + aggregate + bias + ELU ----------
// one block (256 thr = 4 waves) per destination node; no LDS row cache —
// pass 2 re-reads xl rows from the XCD's L2 (hot from pass 1).
__global__ __launch_bounds__(256, 6)
void fused1_k(const int* __restrict__ row_ptr, const int* __restrict__ csr_src,
              const float* __restrict__ xl, const float* __restrict__ xr,
              const float* __restrict__ att, const float* __restrict__ bias,
              float* __restrict__ spill, float* __restrict__ out)
{
    __shared__ float xr_s[HD1];
    __shared__ float lg[LCAP1 * 4];
    __shared__ float smax[4], sinv[4];

    int v = blockIdx.x;
    int t = threadIdx.x;
    int w = t >> 6, lane = t & 63;
    int base = row_ptr[v], deg = row_ptr[v + 1] - base;

    for (int c = t; c < HD1; c += 256) xr_s[c] = xr[(size_t)v * HD1 + c];
    __syncthreads();

    // ---- pass 1: per-edge logits (wave = edge) ----
    int c0 = lane * 8;                   // head = lane>>4
    float4 t0 = *(const float4*)(att + c0);
    float4 t1 = *(const float4*)(att + c0 + 4);
    float4 b0 = *(const float4*)&xr_s[c0];
    float4 b1 = *(const float4*)&xr_s[c0 + 4];
    for (int i = w; i < deg; i += 4) {
        int src = csr_src[base + i];
        const float4* pa = (const float4*)(xl + (size_t)src * HD1 + c0);
        float4 a0 = pa[0], a1 = pa[1];
        float s = t0.x * lrelu(a0.x + b0.x) + t0.y * lrelu(a0.y + b0.y)
                + t0.z * lrelu(a0.z + b0.z) + t0.w * lrelu(a0.w + b0.w)
                + t1.x * lrelu(a1.x + b1.x) + t1.y * lrelu(a1.y + b1.y)
                + t1.z * lrelu(a1.z + b1.z) + t1.w * lrelu(a1.w + b1.w);
        for (int off = 1; off < 16; off <<= 1) s += __shfl_xor(s, off);
        if ((lane & 15) == 0) {
            int h = lane >> 4;
            if (i < LCAP1) lg[i * 4 + h] = s;
            else           spill[(size_t)(base + i) * 4 + h] = s;
        }
    }
    __syncthreads();

    // ---- softmax: wave w owns head w ----
    {
        float m = -INFINITY;
        for (int i = lane; i < deg; i += 64) {
            float lv = (i < LCAP1) ? lg[i * 4 + w] : spill[(size_t)(base + i) * 4 + w];
            m = fmaxf(m, lv);
        }
        for (int off = 1; off < 64; off <<= 1) m = fmaxf(m, __shfl_xor(m, off));
        float s = 0.f;
        for (int i = lane; i < deg; i += 64) {
            float lv = (i < LCAP1) ? lg[i * 4 + w] : spill[(size_t)(base + i) * 4 + w];
            s += expf(lv - m);
        }
        for (int off = 1; off < 64; off <<= 1) s += __shfl_xor(s, off);
        float rs = 1.f / s;
        if (lane == 0) { smax[w] = m; sinv[w] = rs; }
        // normalize in-LDS logits to alphas
        for (int i = lane; i < deg && i < LCAP1; i += 64)
            lg[i * 4 + w] = expf(lg[i * 4 + w] - m) * rs;
    }
    __syncthreads();

    // ---- pass 2: weighted aggregate (channels t and t+256), rows from L2 ----
    int h0 = t >> 7;                     // head of channel t; channel t+256 -> h0+2
    float acc0 = 0.f, acc1 = 0.f;
    for (int i = 0; i < deg; ++i) {
        float a_lo, a_hi;
        if (i < LCAP1) { a_lo = lg[i * 4 + h0]; a_hi = lg[i * 4 + h0 + 2]; }
        else {
            a_lo = expf(spill[(size_t)(base + i) * 4 + h0]     - smax[h0])     * sinv[h0];
            a_hi = expf(spill[(size_t)(base + i) * 4 + h0 + 2] - smax[h0 + 2]) * sinv[h0 + 2];
        }
        const float* row = xl + (size_t)csr_src[base + i] * HD1;
        acc0 += a_lo * row[t];
        acc1 += a_hi * row[t + 256];
    }
    out[(size_t)v * HD1 + t]       = elu(acc0 + bias[t]);
    out[(size_t)v * HD1 + t + 256] = elu(acc1 + bias[t + 256]);
}

// ---------- layer-2 fused: scores + softmax + aggregate + bias + ELU ----------
__global__ __launch_bounds__(256, 8)
void fused2_k(const int* __restrict__ row_ptr, const int* __restrict__ csr_src,
              const float* __restrict__ xl, const float* __restrict__ xr,
              const float* __restrict__ att, const float* __restrict__ bias,
              float* __restrict__ spill, float* __restrict__ out)
{
    __shared__ float xr_s[D2];
    __shared__ float lg[LCAP2];
    __shared__ float part[D2];
    __shared__ float smax_s, sinv_s;

    int v = blockIdx.x;
    int t = threadIdx.x;
    int w = t >> 6, lane = t & 63;
    int base = row_ptr[v], deg = row_ptr[v + 1] - base;

    if (t < D2) xr_s[t] = xr[(size_t)v * D2 + t];
    __syncthreads();

    // ---- pass 1: logits, wave = edge, lane holds 2 channels ----
    int c0 = lane * 2;
    float2 tt = *(const float2*)(att + c0);
    float2 bb = *(const float2*)&xr_s[c0];
    for (int i = w; i < deg; i += 4) {
        int src = csr_src[base + i];
        float2 a = *(const float2*)(xl + (size_t)src * D2 + c0);
        float s = tt.x * lrelu(a.x + bb.x) + tt.y * lrelu(a.y + bb.y);
        for (int off = 1; off < 64; off <<= 1) s += __shfl_xor(s, off);
        if (lane == 0) {
            if (i < LCAP2) lg[i] = s;
            else           spill[base + i] = s;
        }
    }
    __syncthreads();

    // ---- softmax on wave 0 ----
    if (w == 0) {
        float m = -INFINITY;
        for (int i = lane; i < deg; i += 64) {
            float lv = (i < LCAP2) ? lg[i] : spill[base + i];
            m = fmaxf(m, lv);
        }
        for (int off = 1; off < 64; off <<= 1) m = fmaxf(m, __shfl_xor(m, off));
        float s = 0.f;
        for (int i = lane; i < deg; i += 64) {
            float lv = (i < LCAP2) ? lg[i] : spill[base + i];
            s += expf(lv - m);
        }
        for (int off = 1; off < 64; off <<= 1) s += __shfl_xor(s, off);
        float rs = 1.f / s;
        if (lane == 0) { smax_s = m; sinv_s = rs; }
        for (int i = lane; i < deg && i < LCAP2; i += 64)
            lg[i] = expf(lg[i] - m) * rs;
    }
    __syncthreads();

    // ---- pass 2: aggregate; group g handles edges i = g, g+2, ... ----
    int g = t >> 7, c = t & 127;
    float acc = 0.f;
    for (int i = g; i < deg; i += 2) {
        float a = (i < LCAP2) ? lg[i]
                              : expf(spill[base + i] - smax_s) * sinv_s;
        acc += a * xl[(size_t)csr_src[base + i] * D2 + c];
    }
    if (g == 1) part[c] = acc;
    __syncthreads();
    if (g == 0) out[(size_t)v * D2 + c] = elu(acc + part[c] + bias[c]);
}

// ---------- global mean pool ----------
__global__ void pool_k(const int* __restrict__ batch, const float* __restrict__ h,
                       float* __restrict__ out, float* __restrict__ cnt, int N)
{
    int idx = blockIdx.x * 256 + threadIdx.x;
    if (idx >= N * D2) return;
    int v = idx >> 7, c = idx & 127;
    int g = batch[v];
    atomicAdd(&out[(size_t)g * D2 + c], h[idx]);
    if (c == 0) atomicAdd(&cnt[g], 1.0f);
}

__global__ void pooldiv_k(float* __restrict__ out, const float* __restrict__ cnt, int total)
{
    int idx = blockIdx.x * 256 + threadIdx.x;
    if (idx >= total) return;
    out[idx] /= fmaxf(cnt[idx >> 7], 1.0f);
}

extern "C" void kernel_launch(void* const* d_in, const int* in_sizes, int n_in,
                              void* d_out, int out_size, void* d_ws, size_t ws_size,
                              hipStream_t stream)
{
    const float* x    = (const float*)d_in[0];
    const int*   ei   = (const int*)d_in[1];
    const int*   batch= (const int*)d_in[2];
    const float* Wl1  = (const float*)d_in[3];
    const float* bl1  = (const float*)d_in[4];
    const float* Wr1  = (const float*)d_in[5];
    const float* br1  = (const float*)d_in[6];
    const float* att1 = (const float*)d_in[7];
    const float* bias1= (const float*)d_in[8];
    const float* Wl2  = (const float*)d_in[9];
    const float* bl2  = (const float*)d_in[10];
    const float* Wr2  = (const float*)d_in[11];
    const float* br2  = (const float*)d_in[12];
    const float* att2 = (const float*)d_in[13];
    const float* bias2= (const float*)d_in[14];
    float* out = (float*)d_out;

    int N    = in_sizes[2];          // batch vector length = nodes
    int E    = in_sizes[1] / 2;      // directed edges (before self-loops)
    int Etot = E + N;
    int G    = out_size / D2;

    char* ws = (char*)d_ws;
    size_t off = 0;
    auto alloc = [&](size_t bytes) -> void* {
        void* p = ws + off;
        off = (off + bytes + 255) & ~(size_t)255;
        return p;
    };
    float* xl1     = (float*)alloc((size_t)N * HD1 * 4);
    float* xr1     = (float*)alloc((size_t)N * HD1 * 4);  // layer-2 buffers alias here later
    float* h1      = (float*)alloc((size_t)N * HD1 * 4);
    float* spill1  = (float*)alloc((size_t)Etot * 4 * 4);
    int*   counts  = (int*)alloc((size_t)(N + 1) * 4);
    int*   offs    = (int*)alloc((size_t)(N + 1) * 4);
    int*   row_ptr = (int*)alloc((size_t)(N + 1) * 4);
    int*   csr_src = (int*)alloc((size_t)Etot * 4);
    float* poolcnt = (float*)alloc((size_t)(G + 1) * 4);
    // layer-2 aliases inside xr1 (xr1 dead after fused1_k):
    float* xl2     = xr1;
    float* xr2     = xr1 + (size_t)N * D2;
    float* h2      = xr1 + (size_t)2 * N * D2;
    float* spill2  = xr1 + (size_t)3 * N * D2;

    hipMemsetAsync(counts, 0, (size_t)(N + 1) * 4, stream);
    gemm1_k<<<(N + 3) / 4, 256, 0, stream>>>(x, Wl1, bl1, Wr1, br1, xl1, xr1, N);
    count_k<<<(Etot + 255) / 256, 256, 0, stream>>>(ei, E, Etot, counts);
    scan_k<<<1, 1024, 0, stream>>>(counts, row_ptr, offs, N);
    scatter_k<<<(Etot + 255) / 256, 256, 0, stream>>>(ei, E, Etot, offs, csr_src);
    fused1_k<<<N, 256, 0, stream>>>(row_ptr, csr_src, xl1, xr1, att1, bias1, spill1, h1);
    gemm2_k<<<(N + 7) / 8, 256, 0, stream>>>(h1, Wl2, bl2, Wr2, br2, xl2, xr2, N);
    fused2_k<<<N, 256, 0, stream>>>(row_ptr, csr_src, xl2, xr2, att2, bias2, spill2, h2);
    hipMemsetAsync(out, 0, (size_t)out_size * 4, stream);
    hipMemsetAsync(poolcnt, 0, (size_t)G * 4, stream);
    pool_k<<<((N * D2) + 255) / 256, 256, 0, stream>>>(batch, h2, out, poolcnt, N);
    pooldiv_k<<<(out_size + 255) / 256, 256, 0, stream>>>(out, poolcnt, out_size);
}

// Round 6
// 423.039 us; speedup vs baseline: 1.4917x; 1.2051x over previous
//
#include <hip/hip_runtime.h>
#include <hip/hip_fp16.h>
#include <math.h>

#define FIN 78
#define HD1 512
#define D2  128

__device__ __forceinline__ float lrelu(float x) { return x > 0.f ? x : 0.2f * x; }
__device__ __forceinline__ float elu(float x)   { return x > 0.f ? x : expf(x) - 1.f; }

// ---------- layer-1 input GEMM: x[N,78] @ {Wl1,Wr1}[78,512] + bias ----------
// xl stored fp16 (gathered per-edge later), xr stored fp32 (read once per node)
__global__ void gemm1_k(const float* __restrict__ x,
                        const float* __restrict__ Wl, const float* __restrict__ bl,
                        const float* __restrict__ Wr, const float* __restrict__ br,
                        __half* __restrict__ xl, float* __restrict__ xr, int N)
{
    __shared__ float xs[8][FIN];
    int row0 = blockIdx.x * 8;
    int t = threadIdx.x;
    for (int idx = t; idx < 8 * FIN; idx += 256) {
        int r = idx / FIN, k = idx - r * FIN;
        int row = row0 + r;
        xs[r][k] = (row < N) ? x[(size_t)row * FIN + k] : 0.f;
    }
    __syncthreads();
    for (int i = 0; i < 4; ++i) {
        int j = t + i * 256;                 // 0..1023
        const float* W; int col; float b; bool isL;
        if (j < HD1) { W = Wl; col = j;       b = bl[col]; isL = true; }
        else         { W = Wr; col = j - HD1; b = br[col]; isL = false; }
        float acc[8];
#pragma unroll
        for (int r = 0; r < 8; ++r) acc[r] = b;
        for (int k = 0; k < FIN; ++k) {
            float w = W[k * HD1 + col];
#pragma unroll
            for (int r = 0; r < 8; ++r) acc[r] += xs[r][k] * w;
        }
#pragma unroll
        for (int r = 0; r < 8; ++r) {
            int row = row0 + r;
            if (row < N) {
                if (isL) xl[(size_t)row * HD1 + col] = __float2half(acc[r]);
                else     xr[(size_t)row * HD1 + col] = acc[r];
            }
        }
    }
}

// ---------- layer-2 input GEMM: h1[N,512] @ {Wl2,Wr2}[512,128] + bias ----------
__global__ void gemm2_k(const float* __restrict__ h,
                        const float* __restrict__ Wl, const float* __restrict__ bl,
                        const float* __restrict__ Wr, const float* __restrict__ br,
                        __half* __restrict__ xl, float* __restrict__ xr, int N)
{
    __shared__ float hs[8][HD1];
    int row0 = blockIdx.x * 8;
    int t = threadIdx.x;
    for (int idx = t; idx < 8 * HD1; idx += 256) {
        int r = idx >> 9, k = idx & 511;
        int row = row0 + r;
        hs[r][k] = (row < N) ? h[(size_t)row * HD1 + k] : 0.f;
    }
    __syncthreads();
    const float* W; int col; float b; bool isL;
    if (t < D2) { W = Wl; col = t;      b = bl[col]; isL = true; }
    else        { W = Wr; col = t - D2; b = br[col]; isL = false; }
    float acc[8];
#pragma unroll
    for (int r = 0; r < 8; ++r) acc[r] = b;
    for (int k = 0; k < HD1; ++k) {
        float w = W[k * D2 + col];
#pragma unroll
        for (int r = 0; r < 8; ++r) acc[r] += hs[r][k] * w;
    }
#pragma unroll
    for (int r = 0; r < 8; ++r) {
        int row = row0 + r;
        if (row < N) {
            if (isL) xl[(size_t)row * D2 + col] = __float2half(acc[r]);
            else     xr[(size_t)row * D2 + col] = acc[r];
        }
    }
}

// ---------- CSR build over destination nodes ----------
__global__ void count_k(const int* __restrict__ ei, int E, int Etot, int* __restrict__ counts)
{
    int e = blockIdx.x * 256 + threadIdx.x;
    if (e >= Etot) return;
    int dst = (e < E) ? ei[E + e] : (e - E);
    atomicAdd(&counts[dst], 1);
}

__global__ void scan_k(const int* __restrict__ counts, int* __restrict__ row_ptr,
                       int* __restrict__ offs, int N)
{
    __shared__ int sdata[1024];
    int t = threadIdx.x;
    int chunk = (N + 1023) / 1024;
    int lo = t * chunk, hi = min(lo + chunk, N);
    int p = 0;
    for (int i = lo; i < hi; ++i) p += counts[i];
    sdata[t] = p;
    __syncthreads();
    for (int off = 1; off < 1024; off <<= 1) {
        int v = (t >= off) ? sdata[t - off] : 0;
        __syncthreads();
        sdata[t] += v;
        __syncthreads();
    }
    int run = sdata[t] - p;   // exclusive prefix
    for (int i = lo; i < hi; ++i) { row_ptr[i] = run; offs[i] = run; run += counts[i]; }
    if (t == 1023) row_ptr[N] = sdata[1023];
}

__global__ void scatter_k(const int* __restrict__ ei, int E, int Etot,
                          int* __restrict__ offs, int* __restrict__ csr_src)
{
    int e = blockIdx.x * 256 + threadIdx.x;
    if (e >= Etot) return;
    int src, dst;
    if (e < E) { src = ei[e]; dst = ei[E + e]; } else { src = dst = e - E; }
    int pos = atomicAdd(&offs[dst], 1);
    csr_src[pos] = src;
}

// ---------- layer-1 fused: online-softmax GATv2, wave = (node, head) ----------
// block = 1 node, wave w = head w; lane holds channels (128w+2lane, +1).
// Single pass over edges: running max/sum/acc (flash style). No LDS, no syncthreads.
__global__ __launch_bounds__(256, 8)
void fused1_k(const int* __restrict__ row_ptr, const int* __restrict__ csr_src,
              const __half* __restrict__ xl, const float* __restrict__ xr,
              const float* __restrict__ att, const float* __restrict__ bias,
              float* __restrict__ out)
{
    int v = blockIdx.x;
    int t = threadIdx.x;
    int w = t >> 6, lane = t & 63;
    int base = row_ptr[v], deg = row_ptr[v + 1] - base;
    int c0 = (w << 7) + (lane << 1);          // channel pair in [0,512)

    float2 bb = *(const float2*)(xr + (size_t)v * HD1 + c0);
    float2 at = *(const float2*)(att + c0);

    float m = -INFINITY, s = 0.f, a0 = 0.f, a1 = 0.f;
    for (int i = 0; i < deg; ++i) {
        int src = csr_src[base + i];
        __half2 hv = *(const __half2*)(xl + (size_t)src * HD1 + c0);
        float2 af = __half22float2(hv);
        float p = at.x * lrelu(af.x + bb.x) + at.y * lrelu(af.y + bb.y);
#pragma unroll
        for (int off = 1; off < 64; off <<= 1) p += __shfl_xor(p, off);
        float mn = fmaxf(m, p);
        float c  = __expf(m - mn);            // 0 on first iter (m=-inf)
        float e  = __expf(p - mn);
        s  = s * c + e;
        a0 = a0 * c + e * af.x;
        a1 = a1 * c + e * af.y;
        m  = mn;
    }
    float rs = 1.f / s;
    size_t o = (size_t)v * HD1 + c0;
    out[o]     = elu(a0 * rs + bias[c0]);
    out[o + 1] = elu(a1 * rs + bias[c0 + 1]);
}

// ---------- layer-2 fused: online-softmax GATv2, wave = node ----------
__global__ __launch_bounds__(256, 8)
void fused2_k(const int* __restrict__ row_ptr, const int* __restrict__ csr_src,
              const __half* __restrict__ xl, const float* __restrict__ xr,
              const float* __restrict__ att, const float* __restrict__ bias,
              float* __restrict__ out, int N)
{
    int t = threadIdx.x;
    int w = t >> 6, lane = t & 63;
    int v = blockIdx.x * 4 + w;
    if (v >= N) return;
    int base = row_ptr[v], deg = row_ptr[v + 1] - base;
    int c0 = lane << 1;                        // channel pair in [0,128)

    float2 bb = *(const float2*)(xr + (size_t)v * D2 + c0);
    float2 at = *(const float2*)(att + c0);

    float m = -INFINITY, s = 0.f, a0 = 0.f, a1 = 0.f;
    for (int i = 0; i < deg; ++i) {
        int src = csr_src[base + i];
        __half2 hv = *(const __half2*)(xl + (size_t)src * D2 + c0);
        float2 af = __half22float2(hv);
        float p = at.x * lrelu(af.x + bb.x) + at.y * lrelu(af.y + bb.y);
#pragma unroll
        for (int off = 1; off < 64; off <<= 1) p += __shfl_xor(p, off);
        float mn = fmaxf(m, p);
        float c  = __expf(m - mn);
        float e  = __expf(p - mn);
        s  = s * c + e;
        a0 = a0 * c + e * af.x;
        a1 = a1 * c + e * af.y;
        m  = mn;
    }
    float rs = 1.f / s;
    size_t o = (size_t)v * D2 + c0;
    out[o]     = elu(a0 * rs + bias[c0]);
    out[o + 1] = elu(a1 * rs + bias[c0 + 1]);
}

// ---------- global mean pool ----------
__global__ void pool_k(const int* __restrict__ batch, const float* __restrict__ h,
                       float* __restrict__ out, float* __restrict__ cnt, int N)
{
    int idx = blockIdx.x * 256 + threadIdx.x;
    if (idx >= N * D2) return;
    int v = idx >> 7, c = idx & 127;
    int g = batch[v];
    atomicAdd(&out[(size_t)g * D2 + c], h[idx]);
    if (c == 0) atomicAdd(&cnt[g], 1.0f);
}

__global__ void pooldiv_k(float* __restrict__ out, const float* __restrict__ cnt, int total)
{
    int idx = blockIdx.x * 256 + threadIdx.x;
    if (idx >= total) return;
    out[idx] /= fmaxf(cnt[idx >> 7], 1.0f);
}

extern "C" void kernel_launch(void* const* d_in, const int* in_sizes, int n_in,
                              void* d_out, int out_size, void* d_ws, size_t ws_size,
                              hipStream_t stream)
{
    const float* x    = (const float*)d_in[0];
    const int*   ei   = (const int*)d_in[1];
    const int*   batch= (const int*)d_in[2];
    const float* Wl1  = (const float*)d_in[3];
    const float* bl1  = (const float*)d_in[4];
    const float* Wr1  = (const float*)d_in[5];
    const float* br1  = (const float*)d_in[6];
    const float* att1 = (const float*)d_in[7];
    const float* bias1= (const float*)d_in[8];
    const float* Wl2  = (const float*)d_in[9];
    const float* bl2  = (const float*)d_in[10];
    const float* Wr2  = (const float*)d_in[11];
    const float* br2  = (const float*)d_in[12];
    const float* att2 = (const float*)d_in[13];
    const float* bias2= (const float*)d_in[14];
    float* out = (float*)d_out;

    int N    = in_sizes[2];          // batch vector length = nodes
    int E    = in_sizes[1] / 2;      // directed edges (before self-loops)
    int Etot = E + N;
    int G    = out_size / D2;

    char* ws = (char*)d_ws;
    size_t off = 0;
    auto alloc = [&](size_t bytes) -> void* {
        void* p = ws + off;
        off = (off + bytes + 255) & ~(size_t)255;
        return p;
    };
    __half* xl1h   = (__half*)alloc((size_t)N * HD1 * 2);
    float*  xr1    = (float*)alloc((size_t)N * HD1 * 4);
    float*  h1     = (float*)alloc((size_t)N * HD1 * 4);
    __half* xl2h   = (__half*)alloc((size_t)N * D2 * 2);
    float*  xr2    = (float*)alloc((size_t)N * D2 * 4);
    float*  h2     = (float*)alloc((size_t)N * D2 * 4);
    int*    counts = (int*)alloc((size_t)(N + 1) * 4);
    int*    offs   = (int*)alloc((size_t)(N + 1) * 4);
    int*    row_ptr= (int*)alloc((size_t)(N + 1) * 4);
    int*    csr_src= (int*)alloc((size_t)Etot * 4);
    float*  poolcnt= (float*)alloc((size_t)(G + 1) * 4);

    hipMemsetAsync(counts, 0, (size_t)(N + 1) * 4, stream);
    gemm1_k<<<(N + 7) / 8, 256, 0, stream>>>(x, Wl1, bl1, Wr1, br1, xl1h, xr1, N);
    count_k<<<(Etot + 255) / 256, 256, 0, stream>>>(ei, E, Etot, counts);
    scan_k<<<1, 1024, 0, stream>>>(counts, row_ptr, offs, N);
    scatter_k<<<(Etot + 255) / 256, 256, 0, stream>>>(ei, E, Etot, offs, csr_src);
    fused1_k<<<N, 256, 0, stream>>>(row_ptr, csr_src, xl1h, xr1, att1, bias1, h1);
    gemm2_k<<<(N + 7) / 8, 256, 0, stream>>>(h1, Wl2, bl2, Wr2, br2, xl2h, xr2, N);
    fused2_k<<<(N + 3) / 4, 256, 0, stream>>>(row_ptr, csr_src, xl2h, xr2, att2, bias2, h2, N);
    hipMemsetAsync(out, 0, (size_t)out_size * 4, stream);
    hipMemsetAsync(poolcnt, 0, (size_t)G * 4, stream);
    pool_k<<<((N * D2) + 255) / 256, 256, 0, stream>>>(batch, h2, out, poolcnt, N);
    pooldiv_k<<<(out_size + 255) / 256, 256, 0, stream>>>(out, poolcnt, out_size);
}

// Round 7
// 378.449 us; speedup vs baseline: 1.6674x; 1.1178x over previous
//
#include <hip/hip_runtime.h>
#include <hip/hip_fp16.h>
#include <math.h>

#define FIN 78
#define HD1 512
#define D2  128

__device__ __forceinline__ float lrelu(float x) { return x > 0.f ? x : 0.2f * x; }
__device__ __forceinline__ float elu(float x)   { return x > 0.f ? x : expf(x) - 1.f; }

// ---------- layer-1 input GEMM: x[N,78] @ {Wl1,Wr1}[78,512] + bias ----------
__global__ void gemm1_k(const float* __restrict__ x,
                        const float* __restrict__ Wl, const float* __restrict__ bl,
                        const float* __restrict__ Wr, const float* __restrict__ br,
                        __half* __restrict__ xl, float* __restrict__ xr, int N)
{
    __shared__ float xs[8][FIN];
    int row0 = blockIdx.x * 8;
    int t = threadIdx.x;
    for (int idx = t; idx < 8 * FIN; idx += 256) {
        int r = idx / FIN, k = idx - r * FIN;
        int row = row0 + r;
        xs[r][k] = (row < N) ? x[(size_t)row * FIN + k] : 0.f;
    }
    __syncthreads();
    for (int i = 0; i < 4; ++i) {
        int j = t + i * 256;                 // 0..1023
        const float* W; int col; float b; bool isL;
        if (j < HD1) { W = Wl; col = j;       b = bl[col]; isL = true; }
        else         { W = Wr; col = j - HD1; b = br[col]; isL = false; }
        float acc[8];
#pragma unroll
        for (int r = 0; r < 8; ++r) acc[r] = b;
        for (int k = 0; k < FIN; ++k) {
            float w = W[k * HD1 + col];
#pragma unroll
            for (int r = 0; r < 8; ++r) acc[r] += xs[r][k] * w;
        }
#pragma unroll
        for (int r = 0; r < 8; ++r) {
            int row = row0 + r;
            if (row < N) {
                if (isL) xl[(size_t)row * HD1 + col] = __float2half(acc[r]);
                else     xr[(size_t)row * HD1 + col] = acc[r];
            }
        }
    }
}

// ---------- layer-2 input GEMM: h1[N,512] @ {Wl2,Wr2}[512,128] + bias ----------
__global__ void gemm2_k(const float* __restrict__ h,
                        const float* __restrict__ Wl, const float* __restrict__ bl,
                        const float* __restrict__ Wr, const float* __restrict__ br,
                        __half* __restrict__ xl, float* __restrict__ xr, int N)
{
    __shared__ float hs[8][HD1];
    int row0 = blockIdx.x * 8;
    int t = threadIdx.x;
    for (int idx = t; idx < 8 * HD1; idx += 256) {
        int r = idx >> 9, k = idx & 511;
        int row = row0 + r;
        hs[r][k] = (row < N) ? h[(size_t)row * HD1 + k] : 0.f;
    }
    __syncthreads();
    const float* W; int col; float b; bool isL;
    if (t < D2) { W = Wl; col = t;      b = bl[col]; isL = true; }
    else        { W = Wr; col = t - D2; b = br[col]; isL = false; }
    float acc[8];
#pragma unroll
    for (int r = 0; r < 8; ++r) acc[r] = b;
    for (int k = 0; k < HD1; ++k) {
        float w = W[k * D2 + col];
#pragma unroll
        for (int r = 0; r < 8; ++r) acc[r] += hs[r][k] * w;
    }
#pragma unroll
    for (int r = 0; r < 8; ++r) {
        int row = row0 + r;
        if (row < N) {
            if (isL) xl[(size_t)row * D2 + col] = __float2half(acc[r]);
            else     xr[(size_t)row * D2 + col] = acc[r];
        }
    }
}

// ---------- CSR build over destination nodes ----------
__global__ void count_k(const int* __restrict__ ei, int E, int Etot, int* __restrict__ counts)
{
    int e = blockIdx.x * 256 + threadIdx.x;
    if (e >= Etot) return;
    int dst = (e < E) ? ei[E + e] : (e - E);
    atomicAdd(&counts[dst], 1);
}

__global__ void scan_k(const int* __restrict__ counts, int* __restrict__ row_ptr,
                       int* __restrict__ offs, int N)
{
    __shared__ int sdata[1024];
    int t = threadIdx.x;
    int chunk = (N + 1023) / 1024;
    int lo = t * chunk, hi = min(lo + chunk, N);
    int p = 0;
    for (int i = lo; i < hi; ++i) p += counts[i];
    sdata[t] = p;
    __syncthreads();
    for (int off = 1; off < 1024; off <<= 1) {
        int v = (t >= off) ? sdata[t - off] : 0;
        __syncthreads();
        sdata[t] += v;
        __syncthreads();
    }
    int run = sdata[t] - p;   // exclusive prefix
    for (int i = lo; i < hi; ++i) { row_ptr[i] = run; offs[i] = run; run += counts[i]; }
    if (t == 1023) row_ptr[N] = sdata[1023];
}

__global__ void scatter_k(const int* __restrict__ ei, int E, int Etot,
                          int* __restrict__ offs, int* __restrict__ csr_src)
{
    int e = blockIdx.x * 256 + threadIdx.x;
    if (e >= Etot) return;
    int src, dst;
    if (e < E) { src = ei[e]; dst = ei[E + e]; } else { src = dst = e - E; }
    int pos = atomicAdd(&offs[dst], 1);
    csr_src[pos] = src;
}

// ---------- layer-1 fused: block = node, wave = head; 16-lane groups × 4 edges ----------
// lane: group g = lane>>4 handles edges i ≡ g (mod 4); sub = lane&15 covers
// channels [sub*8, sub*8+8) of head w. No max-tracking (logits O(1) by construction;
// softmax is shift-invariant). Group partials merged by 2 shuffles at the end.
__global__ __launch_bounds__(256, 8)
void fused1_k(const int* __restrict__ row_ptr, const int* __restrict__ csr_src,
              const __half* __restrict__ xl, const float* __restrict__ xr,
              const float* __restrict__ att, const float* __restrict__ bias,
              float* __restrict__ out)
{
    int v = blockIdx.x;
    int t = threadIdx.x;
    int w = t >> 6, lane = t & 63;
    int g = lane >> 4, sub = lane & 15;
    int base = row_ptr[v], deg = row_ptr[v + 1] - base;
    int c0 = (w << 7) + (sub << 3);           // channel in [0,512)

    float bb[8], at[8];
    {
        float4 b0 = *(const float4*)(xr + (size_t)v * HD1 + c0);
        float4 b1 = *(const float4*)(xr + (size_t)v * HD1 + c0 + 4);
        float4 t0 = *(const float4*)(att + c0);
        float4 t1 = *(const float4*)(att + c0 + 4);
        bb[0]=b0.x; bb[1]=b0.y; bb[2]=b0.z; bb[3]=b0.w;
        bb[4]=b1.x; bb[5]=b1.y; bb[6]=b1.z; bb[7]=b1.w;
        at[0]=t0.x; at[1]=t0.y; at[2]=t0.z; at[3]=t0.w;
        at[4]=t1.x; at[5]=t1.y; at[6]=t1.z; at[7]=t1.w;
    }

    float s = 0.f, a[8];
#pragma unroll
    for (int j = 0; j < 8; ++j) a[j] = 0.f;

    for (int i = g; i < deg; i += 4) {
        int src = csr_src[base + i];
        uint4 raw = *(const uint4*)(xl + (size_t)src * HD1 + c0);
        const __half2* hp = (const __half2*)&raw;
        float af[8];
#pragma unroll
        for (int j = 0; j < 4; ++j) {
            float2 f = __half22float2(hp[j]);
            af[2*j] = f.x; af[2*j+1] = f.y;
        }
        float p = 0.f;
#pragma unroll
        for (int j = 0; j < 8; ++j) p += at[j] * lrelu(af[j] + bb[j]);
#pragma unroll
        for (int off = 1; off < 16; off <<= 1) p += __shfl_xor(p, off);
        float e = __expf(p);
        s += e;
#pragma unroll
        for (int j = 0; j < 8; ++j) a[j] += e * af[j];
    }
    // merge the 4 groups (lanes sub, sub+16, sub+32, sub+48 hold same channels)
    s += __shfl_xor(s, 16); s += __shfl_xor(s, 32);
#pragma unroll
    for (int j = 0; j < 8; ++j) { a[j] += __shfl_xor(a[j], 16); a[j] += __shfl_xor(a[j], 32); }

    if (g == 0) {
        float rs = 1.f / s;
        float o[8];
#pragma unroll
        for (int j = 0; j < 8; ++j) o[j] = elu(a[j] * rs + bias[c0 + j]);
        size_t ob = (size_t)v * HD1 + c0;
        *(float4*)(out + ob)     = make_float4(o[0], o[1], o[2], o[3]);
        *(float4*)(out + ob + 4) = make_float4(o[4], o[5], o[6], o[7]);
    }
}

// ---------- layer-2 fused + mean-pool epilogue: wave = node ----------
__global__ __launch_bounds__(256, 8)
void fused2_k(const int* __restrict__ row_ptr, const int* __restrict__ csr_src,
              const __half* __restrict__ xl, const float* __restrict__ xr,
              const float* __restrict__ att, const float* __restrict__ bias,
              const int* __restrict__ batch, float* __restrict__ out, int N)
{
    int t = threadIdx.x;
    int w = t >> 6, lane = t & 63;
    int v = blockIdx.x * 4 + w;
    if (v >= N) return;
    int g = lane >> 4, sub = lane & 15;
    int base = row_ptr[v], deg = row_ptr[v + 1] - base;
    int c0 = sub << 3;                          // channel in [0,128)

    float bb[8], at[8];
    {
        float4 b0 = *(const float4*)(xr + (size_t)v * D2 + c0);
        float4 b1 = *(const float4*)(xr + (size_t)v * D2 + c0 + 4);
        float4 t0 = *(const float4*)(att + c0);
        float4 t1 = *(const float4*)(att + c0 + 4);
        bb[0]=b0.x; bb[1]=b0.y; bb[2]=b0.z; bb[3]=b0.w;
        bb[4]=b1.x; bb[5]=b1.y; bb[6]=b1.z; bb[7]=b1.w;
        at[0]=t0.x; at[1]=t0.y; at[2]=t0.z; at[3]=t0.w;
        at[4]=t1.x; at[5]=t1.y; at[6]=t1.z; at[7]=t1.w;
    }

    float s = 0.f, a[8];
#pragma unroll
    for (int j = 0; j < 8; ++j) a[j] = 0.f;

    for (int i = g; i < deg; i += 4) {
        int src = csr_src[base + i];
        uint4 raw = *(const uint4*)(xl + (size_t)src * D2 + c0);
        const __half2* hp = (const __half2*)&raw;
        float af[8];
#pragma unroll
        for (int j = 0; j < 4; ++j) {
            float2 f = __half22float2(hp[j]);
            af[2*j] = f.x; af[2*j+1] = f.y;
        }
        float p = 0.f;
#pragma unroll
        for (int j = 0; j < 8; ++j) p += at[j] * lrelu(af[j] + bb[j]);
#pragma unroll
        for (int off = 1; off < 16; off <<= 1) p += __shfl_xor(p, off);
        float e = __expf(p);
        s += e;
#pragma unroll
        for (int j = 0; j < 8; ++j) a[j] += e * af[j];
    }
    s += __shfl_xor(s, 16); s += __shfl_xor(s, 32);
#pragma unroll
    for (int j = 0; j < 8; ++j) { a[j] += __shfl_xor(a[j], 16); a[j] += __shfl_xor(a[j], 32); }

    if (g == 0) {
        float rs = 1.f / s;
        int grp = batch[v];
        float* ob = out + (size_t)grp * D2 + c0;
#pragma unroll
        for (int j = 0; j < 8; ++j)
            atomicAdd(&ob[j], elu(a[j] * rs + bias[c0 + j]));
    }
}

// ---------- per-graph node counts ----------
__global__ void batchcnt_k(const int* __restrict__ batch, float* __restrict__ cnt, int N)
{
    int v = blockIdx.x * 256 + threadIdx.x;
    if (v >= N) return;
    atomicAdd(&cnt[batch[v]], 1.0f);
}

__global__ void pooldiv_k(float* __restrict__ out, const float* __restrict__ cnt, int total)
{
    int idx = blockIdx.x * 256 + threadIdx.x;
    if (idx >= total) return;
    out[idx] /= fmaxf(cnt[idx >> 7], 1.0f);
}

extern "C" void kernel_launch(void* const* d_in, const int* in_sizes, int n_in,
                              void* d_out, int out_size, void* d_ws, size_t ws_size,
                              hipStream_t stream)
{
    const float* x    = (const float*)d_in[0];
    const int*   ei   = (const int*)d_in[1];
    const int*   batch= (const int*)d_in[2];
    const float* Wl1  = (const float*)d_in[3];
    const float* bl1  = (const float*)d_in[4];
    const float* Wr1  = (const float*)d_in[5];
    const float* br1  = (const float*)d_in[6];
    const float* att1 = (const float*)d_in[7];
    const float* bias1= (const float*)d_in[8];
    const float* Wl2  = (const float*)d_in[9];
    const float* bl2  = (const float*)d_in[10];
    const float* Wr2  = (const float*)d_in[11];
    const float* br2  = (const float*)d_in[12];
    const float* att2 = (const float*)d_in[13];
    const float* bias2= (const float*)d_in[14];
    float* out = (float*)d_out;

    int N    = in_sizes[2];          // batch vector length = nodes
    int E    = in_sizes[1] / 2;      // directed edges (before self-loops)
    int Etot = E + N;
    int G    = out_size / D2;

    char* ws = (char*)d_ws;
    size_t off = 0;
    auto alloc = [&](size_t bytes) -> void* {
        void* p = ws + off;
        off = (off + bytes + 255) & ~(size_t)255;
        return p;
    };
    __half* xl1h   = (__half*)alloc((size_t)N * HD1 * 2);
    float*  xr1    = (float*)alloc((size_t)N * HD1 * 4);
    float*  h1     = (float*)alloc((size_t)N * HD1 * 4);
    __half* xl2h   = (__half*)alloc((size_t)N * D2 * 2);
    float*  xr2    = (float*)alloc((size_t)N * D2 * 4);
    int*    counts = (int*)alloc((size_t)(N + 1) * 4);
    int*    offs   = (int*)alloc((size_t)(N + 1) * 4);
    int*    row_ptr= (int*)alloc((size_t)(N + 1) * 4);
    int*    csr_src= (int*)alloc((size_t)Etot * 4);
    float*  poolcnt= (float*)alloc((size_t)(G + 1) * 4);

    hipMemsetAsync(counts, 0, (size_t)(N + 1) * 4, stream);
    gemm1_k<<<(N + 7) / 8, 256, 0, stream>>>(x, Wl1, bl1, Wr1, br1, xl1h, xr1, N);
    count_k<<<(Etot + 255) / 256, 256, 0, stream>>>(ei, E, Etot, counts);
    scan_k<<<1, 1024, 0, stream>>>(counts, row_ptr, offs, N);
    scatter_k<<<(Etot + 255) / 256, 256, 0, stream>>>(ei, E, Etot, offs, csr_src);
    fused1_k<<<N, 256, 0, stream>>>(row_ptr, csr_src, xl1h, xr1, att1, bias1, h1);
    gemm2_k<<<(N + 7) / 8, 256, 0, stream>>>(h1, Wl2, bl2, Wr2, br2, xl2h, xr2, N);
    hipMemsetAsync(out, 0, (size_t)out_size * 4, stream);
    hipMemsetAsync(poolcnt, 0, (size_t)G * 4, stream);
    fused2_k<<<(N + 3) / 4, 256, 0, stream>>>(row_ptr, csr_src, xl2h, xr2, att2, bias2,
                                              batch, out, N);
    batchcnt_k<<<(N + 255) / 256, 256, 0, stream>>>(batch, poolcnt, N);
    pooldiv_k<<<(out_size + 255) / 256, 256, 0, stream>>>(out, poolcnt, out_size);
}

// Round 8
// 284.800 us; speedup vs baseline: 2.2157x; 1.3288x over previous
//
#include <hip/hip_runtime.h>
#include <hip/hip_fp16.h>
#include <math.h>

#define FIN 78
#define HD1 512
#define D2  128

__device__ __forceinline__ float lrelu(float x) { return x > 0.f ? x : 0.2f * x; }
__device__ __forceinline__ float elu(float x)   { return x > 0.f ? x : expf(x) - 1.f; }

// ---------- layer-1 input GEMM: x[N,78] @ {Wl1,Wr1}[78,512] + bias ----------
__global__ void gemm1_k(const float* __restrict__ x,
                        const float* __restrict__ Wl, const float* __restrict__ bl,
                        const float* __restrict__ Wr, const float* __restrict__ br,
                        __half* __restrict__ xl, float* __restrict__ xr, int N)
{
    __shared__ float xs[8][FIN];
    int row0 = blockIdx.x * 8;
    int t = threadIdx.x;
    for (int idx = t; idx < 8 * FIN; idx += 256) {
        int r = idx / FIN, k = idx - r * FIN;
        int row = row0 + r;
        xs[r][k] = (row < N) ? x[(size_t)row * FIN + k] : 0.f;
    }
    __syncthreads();
    for (int i = 0; i < 4; ++i) {
        int j = t + i * 256;                 // 0..1023
        const float* W; int col; float b; bool isL;
        if (j < HD1) { W = Wl; col = j;       b = bl[col]; isL = true; }
        else         { W = Wr; col = j - HD1; b = br[col]; isL = false; }
        float acc[8];
#pragma unroll
        for (int r = 0; r < 8; ++r) acc[r] = b;
        for (int k = 0; k < FIN; ++k) {
            float w = W[k * HD1 + col];
#pragma unroll
            for (int r = 0; r < 8; ++r) acc[r] += xs[r][k] * w;
        }
#pragma unroll
        for (int r = 0; r < 8; ++r) {
            int row = row0 + r;
            if (row < N) {
                if (isL) xl[(size_t)row * HD1 + col] = __float2half(acc[r]);
                else     xr[(size_t)row * HD1 + col] = acc[r];
            }
        }
    }
}

// ---------- layer-2 input GEMM: h1[N,512] @ {Wl2,Wr2}[512,128] + bias ----------
__global__ void gemm2_k(const float* __restrict__ h,
                        const float* __restrict__ Wl, const float* __restrict__ bl,
                        const float* __restrict__ Wr, const float* __restrict__ br,
                        __half* __restrict__ xl, float* __restrict__ xr, int N)
{
    __shared__ float hs[8][HD1];
    int row0 = blockIdx.x * 8;
    int t = threadIdx.x;
    for (int idx = t; idx < 8 * HD1; idx += 256) {
        int r = idx >> 9, k = idx & 511;
        int row = row0 + r;
        hs[r][k] = (row < N) ? h[(size_t)row * HD1 + k] : 0.f;
    }
    __syncthreads();
    const float* W; int col; float b; bool isL;
    if (t < D2) { W = Wl; col = t;      b = bl[col]; isL = true; }
    else        { W = Wr; col = t - D2; b = br[col]; isL = false; }
    float acc[8];
#pragma unroll
    for (int r = 0; r < 8; ++r) acc[r] = b;
    for (int k = 0; k < HD1; ++k) {
        float w = W[k * D2 + col];
#pragma unroll
        for (int r = 0; r < 8; ++r) acc[r] += hs[r][k] * w;
    }
#pragma unroll
    for (int r = 0; r < 8; ++r) {
        int row = row0 + r;
        if (row < N) {
            if (isL) xl[(size_t)row * D2 + col] = __float2half(acc[r]);
            else     xr[(size_t)row * D2 + col] = acc[r];
        }
    }
}

// ---------- CSR build over destination nodes ----------
__global__ void count_k(const int* __restrict__ ei, int E, int Etot, int* __restrict__ counts)
{
    int e = blockIdx.x * 256 + threadIdx.x;
    if (e >= Etot) return;
    int dst = (e < E) ? ei[E + e] : (e - E);
    atomicAdd(&counts[dst], 1);
}

__global__ void scan_k(const int* __restrict__ counts, int* __restrict__ row_ptr,
                       int* __restrict__ offs, int N)
{
    __shared__ int sdata[1024];
    int t = threadIdx.x;
    int chunk = (N + 1023) / 1024;
    int lo = t * chunk, hi = min(lo + chunk, N);
    int p = 0;
    for (int i = lo; i < hi; ++i) p += counts[i];
    sdata[t] = p;
    __syncthreads();
    for (int off = 1; off < 1024; off <<= 1) {
        int v = (t >= off) ? sdata[t - off] : 0;
        __syncthreads();
        sdata[t] += v;
        __syncthreads();
    }
    int run = sdata[t] - p;   // exclusive prefix
    for (int i = lo; i < hi; ++i) { row_ptr[i] = run; offs[i] = run; run += counts[i]; }
    if (t == 1023) row_ptr[N] = sdata[1023];
}

__global__ void scatter_k(const int* __restrict__ ei, int E, int Etot,
                          int* __restrict__ offs, int* __restrict__ csr_src)
{
    int e = blockIdx.x * 256 + threadIdx.x;
    if (e >= Etot) return;
    int src, dst;
    if (e < E) { src = ei[e]; dst = ei[E + e]; } else { src = dst = e - E; }
    int pos = atomicAdd(&offs[dst], 1);
    csr_src[pos] = src;
}

// ---------- layer-1 fused: block = node, wave = head; 16-lane groups × 4 edges ----------
__global__ __launch_bounds__(256, 8)
void fused1_k(const int* __restrict__ row_ptr, const int* __restrict__ csr_src,
              const __half* __restrict__ xl, const float* __restrict__ xr,
              const float* __restrict__ att, const float* __restrict__ bias,
              float* __restrict__ out)
{
    int v = blockIdx.x;
    int t = threadIdx.x;
    int w = t >> 6, lane = t & 63;
    int g = lane >> 4, sub = lane & 15;
    int base = row_ptr[v], deg = row_ptr[v + 1] - base;
    int c0 = (w << 7) + (sub << 3);           // channel in [0,512)

    float bb[8], at[8];
    {
        float4 b0 = *(const float4*)(xr + (size_t)v * HD1 + c0);
        float4 b1 = *(const float4*)(xr + (size_t)v * HD1 + c0 + 4);
        float4 t0 = *(const float4*)(att + c0);
        float4 t1 = *(const float4*)(att + c0 + 4);
        bb[0]=b0.x; bb[1]=b0.y; bb[2]=b0.z; bb[3]=b0.w;
        bb[4]=b1.x; bb[5]=b1.y; bb[6]=b1.z; bb[7]=b1.w;
        at[0]=t0.x; at[1]=t0.y; at[2]=t0.z; at[3]=t0.w;
        at[4]=t1.x; at[5]=t1.y; at[6]=t1.z; at[7]=t1.w;
    }

    float s = 0.f, a[8];
#pragma unroll
    for (int j = 0; j < 8; ++j) a[j] = 0.f;

    for (int i = g; i < deg; i += 4) {
        int src = csr_src[base + i];
        uint4 raw = *(const uint4*)(xl + (size_t)src * HD1 + c0);
        const __half2* hp = (const __half2*)&raw;
        float af[8];
#pragma unroll
        for (int j = 0; j < 4; ++j) {
            float2 f = __half22float2(hp[j]);
            af[2*j] = f.x; af[2*j+1] = f.y;
        }
        float p = 0.f;
#pragma unroll
        for (int j = 0; j < 8; ++j) p += at[j] * lrelu(af[j] + bb[j]);
#pragma unroll
        for (int off = 1; off < 16; off <<= 1) p += __shfl_xor(p, off);
        float e = __expf(p);
        s += e;
#pragma unroll
        for (int j = 0; j < 8; ++j) a[j] += e * af[j];
    }
    // merge the 4 groups (lanes sub, sub+16, sub+32, sub+48 hold same channels)
    s += __shfl_xor(s, 16); s += __shfl_xor(s, 32);
#pragma unroll
    for (int j = 0; j < 8; ++j) { a[j] += __shfl_xor(a[j], 16); a[j] += __shfl_xor(a[j], 32); }

    if (g == 0) {
        float rs = 1.f / s;
        float o[8];
#pragma unroll
        for (int j = 0; j < 8; ++j) o[j] = elu(a[j] * rs + bias[c0 + j]);
        size_t ob = (size_t)v * HD1 + c0;
        *(float4*)(out + ob)     = make_float4(o[0], o[1], o[2], o[3]);
        *(float4*)(out + ob + 4) = make_float4(o[4], o[5], o[6], o[7]);
    }
}

// ---------- layer-2 fused: wave = node, 16-lane groups × 4 edges; plain h2 write ----------
__global__ __launch_bounds__(256, 8)
void fused2_k(const int* __restrict__ row_ptr, const int* __restrict__ csr_src,
              const __half* __restrict__ xl, const float* __restrict__ xr,
              const float* __restrict__ att, const float* __restrict__ bias,
              float* __restrict__ out, int N)
{
    int t = threadIdx.x;
    int w = t >> 6, lane = t & 63;
    int v = blockIdx.x * 4 + w;
    if (v >= N) return;
    int g = lane >> 4, sub = lane & 15;
    int base = row_ptr[v], deg = row_ptr[v + 1] - base;
    int c0 = sub << 3;                          // channel in [0,128)

    float bb[8], at[8];
    {
        float4 b0 = *(const float4*)(xr + (size_t)v * D2 + c0);
        float4 b1 = *(const float4*)(xr + (size_t)v * D2 + c0 + 4);
        float4 t0 = *(const float4*)(att + c0);
        float4 t1 = *(const float4*)(att + c0 + 4);
        bb[0]=b0.x; bb[1]=b0.y; bb[2]=b0.z; bb[3]=b0.w;
        bb[4]=b1.x; bb[5]=b1.y; bb[6]=b1.z; bb[7]=b1.w;
        at[0]=t0.x; at[1]=t0.y; at[2]=t0.z; at[3]=t0.w;
        at[4]=t1.x; at[5]=t1.y; at[6]=t1.z; at[7]=t1.w;
    }

    float s = 0.f, a[8];
#pragma unroll
    for (int j = 0; j < 8; ++j) a[j] = 0.f;

    for (int i = g; i < deg; i += 4) {
        int src = csr_src[base + i];
        uint4 raw = *(const uint4*)(xl + (size_t)src * D2 + c0);
        const __half2* hp = (const __half2*)&raw;
        float af[8];
#pragma unroll
        for (int j = 0; j < 4; ++j) {
            float2 f = __half22float2(hp[j]);
            af[2*j] = f.x; af[2*j+1] = f.y;
        }
        float p = 0.f;
#pragma unroll
        for (int j = 0; j < 8; ++j) p += at[j] * lrelu(af[j] + bb[j]);
#pragma unroll
        for (int off = 1; off < 16; off <<= 1) p += __shfl_xor(p, off);
        float e = __expf(p);
        s += e;
#pragma unroll
        for (int j = 0; j < 8; ++j) a[j] += e * af[j];
    }
    s += __shfl_xor(s, 16); s += __shfl_xor(s, 32);
#pragma unroll
    for (int j = 0; j < 8; ++j) { a[j] += __shfl_xor(a[j], 16); a[j] += __shfl_xor(a[j], 32); }

    if (g == 0) {
        float rs = 1.f / s;
        float o[8];
#pragma unroll
        for (int j = 0; j < 8; ++j) o[j] = elu(a[j] * rs + bias[c0 + j]);
        size_t ob = (size_t)v * D2 + c0;
        *(float4*)(out + ob)     = make_float4(o[0], o[1], o[2], o[3]);
        *(float4*)(out + ob + 4) = make_float4(o[4], o[5], o[6], o[7]);
    }
}

// ---------- graph boundaries: gb[g] = first node with batch[v] >= g ----------
__global__ void gb_k(const int* __restrict__ batch, int* __restrict__ gb, int N, int G)
{
    int g = blockIdx.x * 128 + threadIdx.x;
    if (g > G) return;
    int lo = 0, hi = N;
    while (lo < hi) {
        int mid = (lo + hi) >> 1;
        if (batch[mid] < g) lo = mid + 1; else hi = mid;
    }
    gb[g] = lo;
}

// ---------- mean pool: one block per graph, no atomics ----------
__global__ void pool2_k(const int* __restrict__ gb, const float* __restrict__ h,
                        float* __restrict__ out)
{
    __shared__ float part[D2];
    int g = blockIdx.x;
    int t = threadIdx.x;
    int c = t & 127, half = t >> 7;
    int lo = gb[g], hi = gb[g + 1];
    float acc = 0.f;
    for (int v = lo + half; v < hi; v += 2)
        acc += h[(size_t)v * D2 + c];
    if (half == 1) part[c] = acc;
    __syncthreads();
    if (half == 0) {
        float tot = acc + part[c];
        float cnt = (float)max(hi - lo, 1);
        out[(size_t)g * D2 + c] = tot / cnt;
    }
}

extern "C" void kernel_launch(void* const* d_in, const int* in_sizes, int n_in,
                              void* d_out, int out_size, void* d_ws, size_t ws_size,
                              hipStream_t stream)
{
    const float* x    = (const float*)d_in[0];
    const int*   ei   = (const int*)d_in[1];
    const int*   batch= (const int*)d_in[2];
    const float* Wl1  = (const float*)d_in[3];
    const float* bl1  = (const float*)d_in[4];
    const float* Wr1  = (const float*)d_in[5];
    const float* br1  = (const float*)d_in[6];
    const float* att1 = (const float*)d_in[7];
    const float* bias1= (const float*)d_in[8];
    const float* Wl2  = (const float*)d_in[9];
    const float* bl2  = (const float*)d_in[10];
    const float* Wr2  = (const float*)d_in[11];
    const float* br2  = (const float*)d_in[12];
    const float* att2 = (const float*)d_in[13];
    const float* bias2= (const float*)d_in[14];
    float* out = (float*)d_out;

    int N    = in_sizes[2];          // batch vector length = nodes
    int E    = in_sizes[1] / 2;      // directed edges (before self-loops)
    int Etot = E + N;
    int G    = out_size / D2;

    char* ws = (char*)d_ws;
    size_t off = 0;
    auto alloc = [&](size_t bytes) -> void* {
        void* p = ws + off;
        off = (off + bytes + 255) & ~(size_t)255;
        return p;
    };
    __half* xl1h   = (__half*)alloc((size_t)N * HD1 * 2);
    float*  xr1    = (float*)alloc((size_t)N * HD1 * 4);
    float*  h1     = (float*)alloc((size_t)N * HD1 * 4);
    __half* xl2h   = (__half*)alloc((size_t)N * D2 * 2);
    float*  xr2    = (float*)alloc((size_t)N * D2 * 4);
    float*  h2     = (float*)alloc((size_t)N * D2 * 4);
    int*    counts = (int*)alloc((size_t)(N + 1) * 4);
    int*    offs   = (int*)alloc((size_t)(N + 1) * 4);
    int*    row_ptr= (int*)alloc((size_t)(N + 1) * 4);
    int*    csr_src= (int*)alloc((size_t)Etot * 4);
    int*    gb     = (int*)alloc((size_t)(G + 1) * 4);

    hipMemsetAsync(counts, 0, (size_t)(N + 1) * 4, stream);
    gemm1_k<<<(N + 7) / 8, 256, 0, stream>>>(x, Wl1, bl1, Wr1, br1, xl1h, xr1, N);
    count_k<<<(Etot + 255) / 256, 256, 0, stream>>>(ei, E, Etot, counts);
    scan_k<<<1, 1024, 0, stream>>>(counts, row_ptr, offs, N);
    scatter_k<<<(Etot + 255) / 256, 256, 0, stream>>>(ei, E, Etot, offs, csr_src);
    fused1_k<<<N, 256, 0, stream>>>(row_ptr, csr_src, xl1h, xr1, att1, bias1, h1);
    gemm2_k<<<(N + 7) / 8, 256, 0, stream>>>(h1, Wl2, bl2, Wr2, br2, xl2h, xr2, N);
    fused2_k<<<(N + 3) / 4, 256, 0, stream>>>(row_ptr, csr_src, xl2h, xr2, att2, bias2, h2, N);
    gb_k<<<1, 128, 0, stream>>>(batch, gb, N, G);
    pool2_k<<<G, 256, 0, stream>>>(gb, h2, out);
}

// Round 11
// 276.467 us; speedup vs baseline: 2.2825x; 1.0301x over previous
//
#include <hip/hip_runtime.h>
#include <hip/hip_fp16.h>
#include <math.h>

#define FIN 78
#define HD1 512
#define D2  128

typedef _Float16 f16x2 __attribute__((ext_vector_type(2)));
union U2H { unsigned u; f16x2 h; __half2 hh; };
__device__ __forceinline__ f16x2 u2h(unsigned u) { U2H x; x.u = u; return x.h; }

__device__ __forceinline__ float lrelu(float x) { return x > 0.f ? x : 0.2f * x; }
__device__ __forceinline__ float elu(float x)   { return x > 0.f ? x : expf(x) - 1.f; }

// ---------- layer-1 input GEMM: x[N,78] @ {Wl1,Wr1}[78,512] + bias ----------
__global__ void gemm1_k(const float* __restrict__ x,
                        const float* __restrict__ Wl, const float* __restrict__ bl,
                        const float* __restrict__ Wr, const float* __restrict__ br,
                        __half* __restrict__ xl, float* __restrict__ xr, int N)
{
    __shared__ float xs[8][FIN];
    int row0 = blockIdx.x * 8;
    int t = threadIdx.x;
    for (int idx = t; idx < 8 * FIN; idx += 256) {
        int r = idx / FIN, k = idx - r * FIN;
        int row = row0 + r;
        xs[r][k] = (row < N) ? x[(size_t)row * FIN + k] : 0.f;
    }
    __syncthreads();
    for (int i = 0; i < 4; ++i) {
        int j = t + i * 256;                 // 0..1023
        const float* W; int col; float b; bool isL;
        if (j < HD1) { W = Wl; col = j;       b = bl[col]; isL = true; }
        else         { W = Wr; col = j - HD1; b = br[col]; isL = false; }
        float acc[8];
#pragma unroll
        for (int r = 0; r < 8; ++r) acc[r] = b;
        for (int k = 0; k < FIN; ++k) {
            float w = W[k * HD1 + col];
#pragma unroll
            for (int r = 0; r < 8; ++r) acc[r] += xs[r][k] * w;
        }
#pragma unroll
        for (int r = 0; r < 8; ++r) {
            int row = row0 + r;
            if (row < N) {
                if (isL) xl[(size_t)row * HD1 + col] = __float2half(acc[r]);
                else     xr[(size_t)row * HD1 + col] = acc[r];
            }
        }
    }
}

// ---------- W2 transpose+pack: [512][128]x2 fp32 -> Wt[256 cols][256 k2] half2 ----------
__global__ void cvtW2_k(const float* __restrict__ Wl, const float* __restrict__ Wr,
                        unsigned* __restrict__ Wt)
{
    int idx = blockIdx.x * 256 + threadIdx.x;   // 65536 = 256 cols * 256 k2
    int col = idx >> 8, k2 = idx & 255;
    float w0, w1;
    if (col < D2) { w0 = Wl[(2 * k2) * D2 + col];       w1 = Wl[(2 * k2 + 1) * D2 + col]; }
    else          { int cc = col - D2;
                    w0 = Wr[(2 * k2) * D2 + cc];        w1 = Wr[(2 * k2 + 1) * D2 + cc]; }
    U2H x; x.hh = __floats2half2_rn(w0, w1);
    Wt[idx] = x.u;                               // idx == col*256 + k2
}

// ---------- layer-2 input GEMM via v_dot2_f32_f16: h1[N,512]f16 @ Wt ----------
// block: 16 rows x 256 cols; thread: 8 rows x 2 cols; k in pairs.
__global__ __launch_bounds__(256, 4)
void gemm2_k(const __half* __restrict__ h, const unsigned* __restrict__ Wt,
             const float* __restrict__ bl, const float* __restrict__ br,
             __half* __restrict__ xl, float* __restrict__ xr, int N)
{
    __shared__ unsigned hs[16][256];             // 16 rows x 256 k-pairs
    int row0 = blockIdx.x * 16;
    int t = threadIdx.x;
    for (int idx = t; idx < 16 * 64; idx += 256) {   // 1024 uint4 loads
        int r = idx >> 6, q = idx & 63;
        int row = row0 + r;
        uint4 val = make_uint4(0u, 0u, 0u, 0u);
        if (row < N) val = *(const uint4*)(h + (size_t)row * HD1 + q * 8);
        *(uint4*)&hs[r][q * 4] = val;
    }
    __syncthreads();

    int c = t & 127, rg = t >> 7;                // cols 2c,2c+1; rows rg*8..rg*8+7
    const unsigned* w0p = Wt + (size_t)(2 * c)     * 256;
    const unsigned* w1p = Wt + (size_t)(2 * c + 1) * 256;
    float acc[8][2];
#pragma unroll
    for (int r = 0; r < 8; ++r) { acc[r][0] = 0.f; acc[r][1] = 0.f; }

    for (int k2 = 0; k2 < 256; ++k2) {
        f16x2 w0 = u2h(w0p[k2]);
        f16x2 w1 = u2h(w1p[k2]);
#pragma unroll
        for (int r = 0; r < 8; ++r) {
            f16x2 hv = u2h(hs[rg * 8 + r][k2]);
            acc[r][0] = __builtin_amdgcn_fdot2(hv, w0, acc[r][0], false);
            acc[r][1] = __builtin_amdgcn_fdot2(hv, w1, acc[r][1], false);
        }
    }

    if (c < 64) {
        int cc = 2 * c;
        float b0 = bl[cc], b1 = bl[cc + 1];
#pragma unroll
        for (int r = 0; r < 8; ++r) {
            int row = row0 + rg * 8 + r;
            if (row < N)
                *(__half2*)(xl + (size_t)row * D2 + cc) =
                    __floats2half2_rn(acc[r][0] + b0, acc[r][1] + b1);
        }
    } else {
        int cc = 2 * c - 128;
        float b0 = br[cc], b1 = br[cc + 1];
#pragma unroll
        for (int r = 0; r < 8; ++r) {
            int row = row0 + rg * 8 + r;
            if (row < N)
                *(float2*)(xr + (size_t)row * D2 + cc) =
                    make_float2(acc[r][0] + b0, acc[r][1] + b1);
        }
    }
}

// ---------- CSR build over destination nodes ----------
__global__ void count_k(const int* __restrict__ ei, int E, int Etot, int* __restrict__ counts)
{
    int e = blockIdx.x * 256 + threadIdx.x;
    if (e >= Etot) return;
    int dst = (e < E) ? ei[E + e] : (e - E);
    atomicAdd(&counts[dst], 1);
}

__global__ void scan_k(const int* __restrict__ counts, int* __restrict__ row_ptr,
                       int* __restrict__ offs, int N)
{
    __shared__ int sdata[1024];
    int t = threadIdx.x;
    int chunk = (N + 1023) / 1024;
    int lo = t * chunk, hi = min(lo + chunk, N);
    int p = 0;
    for (int i = lo; i < hi; ++i) p += counts[i];
    sdata[t] = p;
    __syncthreads();
    for (int off = 1; off < 1024; off <<= 1) {
        int v = (t >= off) ? sdata[t - off] : 0;
        __syncthreads();
        sdata[t] += v;
        __syncthreads();
    }
    int run = sdata[t] - p;   // exclusive prefix
    for (int i = lo; i < hi; ++i) { row_ptr[i] = run; offs[i] = run; run += counts[i]; }
    if (t == 1023) row_ptr[N] = sdata[1023];
}

__global__ void scatter_k(const int* __restrict__ ei, int E, int Etot,
                          int* __restrict__ offs, int* __restrict__ csr_src)
{
    int e = blockIdx.x * 256 + threadIdx.x;
    if (e >= Etot) return;
    int src, dst;
    if (e < E) { src = ei[e]; dst = ei[E + e]; } else { src = dst = e - E; }
    int pos = atomicAdd(&offs[dst], 1);
    csr_src[pos] = src;
}

// ---------- layer-1 fused: block = node, wave = head; 16-lane groups × 4 edges ----------
// h1 written as fp16 (only consumer is gemm2_k).
__global__ __launch_bounds__(256, 8)
void fused1_k(const int* __restrict__ row_ptr, const int* __restrict__ csr_src,
              const __half* __restrict__ xl, const float* __restrict__ xr,
              const float* __restrict__ att, const float* __restrict__ bias,
              __half* __restrict__ out)
{
    int v = blockIdx.x;
    int t = threadIdx.x;
    int w = t >> 6, lane = t & 63;
    int g = lane >> 4, sub = lane & 15;
    int base = row_ptr[v], deg = row_ptr[v + 1] - base;
    int c0 = (w << 7) + (sub << 3);           // channel in [0,512)

    float bb[8], at[8];
    {
        float4 b0 = *(const float4*)(xr + (size_t)v * HD1 + c0);
        float4 b1 = *(const float4*)(xr + (size_t)v * HD1 + c0 + 4);
        float4 t0 = *(const float4*)(att + c0);
        float4 t1 = *(const float4*)(att + c0 + 4);
        bb[0]=b0.x; bb[1]=b0.y; bb[2]=b0.z; bb[3]=b0.w;
        bb[4]=b1.x; bb[5]=b1.y; bb[6]=b1.z; bb[7]=b1.w;
        at[0]=t0.x; at[1]=t0.y; at[2]=t0.z; at[3]=t0.w;
        at[4]=t1.x; at[5]=t1.y; at[6]=t1.z; at[7]=t1.w;
    }

    float s = 0.f, a[8];
#pragma unroll
    for (int j = 0; j < 8; ++j) a[j] = 0.f;

    for (int i = g; i < deg; i += 4) {
        int src = csr_src[base + i];
        uint4 raw = *(const uint4*)(xl + (size_t)src * HD1 + c0);
        const __half2* hp = (const __half2*)&raw;
        float af[8];
#pragma unroll
        for (int j = 0; j < 4; ++j) {
            float2 f = __half22float2(hp[j]);
            af[2*j] = f.x; af[2*j+1] = f.y;
        }
        float p = 0.f;
#pragma unroll
        for (int j = 0; j < 8; ++j) p += at[j] * lrelu(af[j] + bb[j]);
#pragma unroll
        for (int off = 1; off < 16; off <<= 1) p += __shfl_xor(p, off);
        float e = __expf(p);
        s += e;
#pragma unroll
        for (int j = 0; j < 8; ++j) a[j] += e * af[j];
    }
    s += __shfl_xor(s, 16); s += __shfl_xor(s, 32);
#pragma unroll
    for (int j = 0; j < 8; ++j) { a[j] += __shfl_xor(a[j], 16); a[j] += __shfl_xor(a[j], 32); }

    if (g == 0) {
        float rs = 1.f / s;
        union { __half2 h2[4]; uint4 u; } pk;
#pragma unroll
        for (int j = 0; j < 4; ++j)
            pk.h2[j] = __floats2half2_rn(elu(a[2*j]   * rs + bias[c0 + 2*j]),
                                         elu(a[2*j+1] * rs + bias[c0 + 2*j+1]));
        *(uint4*)(out + (size_t)v * HD1 + c0) = pk.u;
    }
}

// ---------- layer-2 fused: wave = node, 16-lane groups × 4 edges; plain h2 write ----------
__global__ __launch_bounds__(256, 8)
void fused2_k(const int* __restrict__ row_ptr, const int* __restrict__ csr_src,
              const __half* __restrict__ xl, const float* __restrict__ xr,
              const float* __restrict__ att, const float* __restrict__ bias,
              float* __restrict__ out, int N)
{
    int t = threadIdx.x;
    int w = t >> 6, lane = t & 63;
    int v = blockIdx.x * 4 + w;
    if (v >= N) return;
    int g = lane >> 4, sub = lane & 15;
    int base = row_ptr[v], deg = row_ptr[v + 1] - base;
    int c0 = sub << 3;                          // channel in [0,128)

    float bb[8], at[8];
    {
        float4 b0 = *(const float4*)(xr + (size_t)v * D2 + c0);
        float4 b1 = *(const float4*)(xr + (size_t)v * D2 + c0 + 4);
        float4 t0 = *(const float4*)(att + c0);
        float4 t1 = *(const float4*)(att + c0 + 4);
        bb[0]=b0.x; bb[1]=b0.y; bb[2]=b0.z; bb[3]=b0.w;
        bb[4]=b1.x; bb[5]=b1.y; bb[6]=b1.z; bb[7]=b1.w;
        at[0]=t0.x; at[1]=t0.y; at[2]=t0.z; at[3]=t0.w;
        at[4]=t1.x; at[5]=t1.y; at[6]=t1.z; at[7]=t1.w;
    }

    float s = 0.f, a[8];
#pragma unroll
    for (int j = 0; j < 8; ++j) a[j] = 0.f;

    for (int i = g; i < deg; i += 4) {
        int src = csr_src[base + i];
        uint4 raw = *(const uint4*)(xl + (size_t)src * D2 + c0);
        const __half2* hp = (const __half2*)&raw;
        float af[8];
#pragma unroll
        for (int j = 0; j < 4; ++j) {
            float2 f = __half22float2(hp[j]);
            af[2*j] = f.x; af[2*j+1] = f.y;
        }
        float p = 0.f;
#pragma unroll
        for (int j = 0; j < 8; ++j) p += at[j] * lrelu(af[j] + bb[j]);
#pragma unroll
        for (int off = 1; off < 16; off <<= 1) p += __shfl_xor(p, off);
        float e = __expf(p);
        s += e;
#pragma unroll
        for (int j = 0; j < 8; ++j) a[j] += e * af[j];
    }
    s += __shfl_xor(s, 16); s += __shfl_xor(s, 32);
#pragma unroll
    for (int j = 0; j < 8; ++j) { a[j] += __shfl_xor(a[j], 16); a[j] += __shfl_xor(a[j], 32); }

    if (g == 0) {
        float rs = 1.f / s;
        float o[8];
#pragma unroll
        for (int j = 0; j < 8; ++j) o[j] = elu(a[j] * rs + bias[c0 + j]);
        size_t ob = (size_t)v * D2 + c0;
        *(float4*)(out + ob)     = make_float4(o[0], o[1], o[2], o[3]);
        *(float4*)(out + ob + 4) = make_float4(o[4], o[5], o[6], o[7]);
    }
}

// ---------- graph boundaries: gb[g] = first node with batch[v] >= g ----------
__global__ void gb_k(const int* __restrict__ batch, int* __restrict__ gb, int N, int G)
{
    int g = blockIdx.x * 128 + threadIdx.x;
    if (g > G) return;
    int lo = 0, hi = N;
    while (lo < hi) {
        int mid = (lo + hi) >> 1;
        if (batch[mid] < g) lo = mid + 1; else hi = mid;
    }
    gb[g] = lo;
}

// ---------- mean pool: one block per graph, no atomics ----------
__global__ void pool2_k(const int* __restrict__ gb, const float* __restrict__ h,
                        float* __restrict__ out)
{
    __shared__ float part[D2];
    int g = blockIdx.x;
    int t = threadIdx.x;
    int c = t & 127, half = t >> 7;
    int lo = gb[g], hi = gb[g + 1];
    float acc = 0.f;
    for (int v = lo + half; v < hi; v += 2)
        acc += h[(size_t)v * D2 + c];
    if (half == 1) part[c] = acc;
    __syncthreads();
    if (half == 0) {
        float tot = acc + part[c];
        float cnt = (float)max(hi - lo, 1);
        out[(size_t)g * D2 + c] = tot / cnt;
    }
}

extern "C" void kernel_launch(void* const* d_in, const int* in_sizes, int n_in,
                              void* d_out, int out_size, void* d_ws, size_t ws_size,
                              hipStream_t stream)
{
    const float* x    = (const float*)d_in[0];
    const int*   ei   = (const int*)d_in[1];
    const int*   batch= (const int*)d_in[2];
    const float* Wl1  = (const float*)d_in[3];
    const float* bl1  = (const float*)d_in[4];
    const float* Wr1  = (const float*)d_in[5];
    const float* br1  = (const float*)d_in[6];
    const float* att1 = (const float*)d_in[7];
    const float* bias1= (const float*)d_in[8];
    const float* Wl2  = (const float*)d_in[9];
    const float* bl2  = (const float*)d_in[10];
    const float* Wr2  = (const float*)d_in[11];
    const float* br2  = (const float*)d_in[12];
    const float* att2 = (const float*)d_in[13];
    const float* bias2= (const float*)d_in[14];
    float* out = (float*)d_out;

    int N    = in_sizes[2];          // batch vector length = nodes
    int E    = in_sizes[1] / 2;      // directed edges (before self-loops)
    int Etot = E + N;
    int G    = out_size / D2;

    char* ws = (char*)d_ws;
    size_t off = 0;
    auto alloc = [&](size_t bytes) -> void* {
        void* p = ws + off;
        off = (off + bytes + 255) & ~(size_t)255;
        return p;
    };
    __half*   xl1h   = (__half*)alloc((size_t)N * HD1 * 2);
    float*    xr1    = (float*)alloc((size_t)N * HD1 * 4);
    __half*   h1h    = (__half*)alloc((size_t)N * HD1 * 2);
    __half*   xl2h   = (__half*)alloc((size_t)N * D2 * 2);
    float*    xr2    = (float*)alloc((size_t)N * D2 * 4);
    float*    h2     = (float*)alloc((size_t)N * D2 * 4);
    unsigned* Wt2    = (unsigned*)alloc((size_t)256 * 256 * 4);
    int*      counts = (int*)alloc((size_t)(N + 1) * 4);
    int*      offs   = (int*)alloc((size_t)(N + 1) * 4);
    int*      row_ptr= (int*)alloc((size_t)(N + 1) * 4);
    int*      csr_src= (int*)alloc((size_t)Etot * 4);
    int*      gb     = (int*)alloc((size_t)(G + 1) * 4);

    hipMemsetAsync(counts, 0, (size_t)(N + 1) * 4, stream);
    cvtW2_k<<<256, 256, 0, stream>>>(Wl2, Wr2, Wt2);
    gemm1_k<<<(N + 7) / 8, 256, 0, stream>>>(x, Wl1, bl1, Wr1, br1, xl1h, xr1, N);
    count_k<<<(Etot + 255) / 256, 256, 0, stream>>>(ei, E, Etot, counts);
    scan_k<<<1, 1024, 0, stream>>>(counts, row_ptr, offs, N);
    scatter_k<<<(Etot + 255) / 256, 256, 0, stream>>>(ei, E, Etot, offs, csr_src);
    fused1_k<<<N, 256, 0, stream>>>(row_ptr, csr_src, xl1h, xr1, att1, bias1, h1h);
    gemm2_k<<<(N + 15) / 16, 256, 0, stream>>>(h1h, Wt2, bl2, br2, xl2h, xr2, N);
    fused2_k<<<(N + 3) / 4, 256, 0, stream>>>(row_ptr, csr_src, xl2h, xr2, att2, bias2, h2, N);
    gb_k<<<1, 128, 0, stream>>>(batch, gb, N, G);
    pool2_k<<<G, 256, 0, stream>>>(gb, h2, out);
}